// Round 9
// baseline (339.740 us; speedup 1.0000x reference)
//
#include <hip/hip_runtime.h>
#include <hip/hip_bf16.h>
#include <math.h>

#define D_MODEL 512
#define N_HEADS 8
#define D_K     64
#define D_FF    2048
#define B_      2
#define S_      2048
#define M_TOT   (B_ * S_)   // 4096
#define NSPLIT  4           // KV-axis split for attention occupancy

// log2(e) folded into Q scale: softmax(s) == 2^(s*log2e) normalized
#define QSCALE  0.18033688011112042f   // 0.125 * 1.4426950408889634

typedef __attribute__((ext_vector_type(8))) __bf16 bf16x8;
typedef __attribute__((ext_vector_type(4))) __bf16 bf16x4;
typedef __attribute__((ext_vector_type(4))) float  f32x4;
typedef __attribute__((ext_vector_type(4))) unsigned int u32x4;

static __device__ inline f32x4 mfma16(bf16x8 a, bf16x8 b, f32x4 c) {
    return __builtin_amdgcn_mfma_f32_16x16x32_bf16(a, b, c, 0, 0, 0);
}

static __device__ inline void gld_lds16(const __bf16* g, __bf16* l) {
    __builtin_amdgcn_global_load_lds(
        (const __attribute__((address_space(1))) void*)g,
        (__attribute__((address_space(3))) void*)l, 16, 0, 0);
}

static __device__ inline unsigned int pack_bf16(float a, float b) {
    union { __bf16 h; unsigned short u; } ua, ub;
    ua.h = (__bf16)a; ub.h = (__bf16)b;
    return (unsigned int)ua.u | ((unsigned int)ub.u << 16);
}

// ================= fused prep: x->bf16 + LDS-tiled weight transposes ==========
// blocks [0,2048): x cvt (x4 vec). blocks [2048,2816): 64x64 transpose tiles.
//  tile tt = bid-2048:
//   [0,64)    wq -> wqkvT+0        (8x8 tiles)
//   [64,128)  wk -> wqkvT+262144
//   [128,192) wv -> wqkvT+524288
//   [192,256) wo -> woT
//   [256,512) w1 -> w1T  (K=512,N=2048: 8x32 tiles)
//   [512,768) w2 -> w2T  (K=2048,N=512: 32x8 tiles)
__global__ __launch_bounds__(256) void k_prep(const float* __restrict__ x,
                                              const float* __restrict__ wq,
                                              const float* __restrict__ wk,
                                              const float* __restrict__ wv,
                                              const float* __restrict__ wo,
                                              const float* __restrict__ w1,
                                              const float* __restrict__ w2,
                                              __bf16* __restrict__ xb,
                                              __bf16* __restrict__ wqkvT,
                                              __bf16* __restrict__ woT,
                                              __bf16* __restrict__ w1T,
                                              __bf16* __restrict__ w2T) {
    int bid = blockIdx.x, tid = threadIdx.x;
    if (bid < 2048) {
        int i = (bid * 256 + tid) * 4;
        float4 f = *(const float4*)(x + i);
        bf16x4 o = { (__bf16)f.x, (__bf16)f.y, (__bf16)f.z, (__bf16)f.w };
        *(bf16x4*)(xb + i) = o;
        return;
    }
    __shared__ __bf16 t64[64 * 72];   // [n][k], stride 72 (pad) = 9216 B
    int tt = bid - 2048;
    const float* W; __bf16* WT; int N, K, ntiles, local;
    if (tt < 256) {
        N = 512; K = 512; ntiles = 8;
        if (tt < 64)       { W = wq; WT = wqkvT;          local = tt; }
        else if (tt < 128) { W = wk; WT = wqkvT + 262144; local = tt - 64; }
        else if (tt < 192) { W = wv; WT = wqkvT + 524288; local = tt - 128; }
        else               { W = wo; WT = woT;            local = tt - 192; }
    } else if (tt < 512)   { W = w1; WT = w1T; N = 2048; K = 512;  ntiles = 32; local = tt - 256; }
    else                   { W = w2; WT = w2T; N = 512;  K = 2048; ntiles = 8;  local = tt - 512; }
    int k0 = (local / ntiles) * 64, n0 = (local % ntiles) * 64;

    // read: coalesced float4, write transposed into LDS
#pragma unroll
    for (int it = 0; it < 4; it++) {
        int i = it * 256 + tid;
        int r = i >> 4, c4 = i & 15;
        float4 v = ((const float4*)(W + (size_t)(k0 + r) * N + n0))[c4];
        t64[(c4 * 4 + 0) * 72 + r] = (__bf16)v.x;
        t64[(c4 * 4 + 1) * 72 + r] = (__bf16)v.y;
        t64[(c4 * 4 + 2) * 72 + r] = (__bf16)v.z;
        t64[(c4 * 4 + 3) * 72 + r] = (__bf16)v.w;
    }
    __syncthreads();
    // write: 16B chunks, coalesced per output row
#pragma unroll
    for (int it = 0; it < 2; it++) {
        int j = it * 256 + tid;
        int n = j >> 3, c8 = j & 7;
        bf16x8 v = *(const bf16x8*)&t64[n * 72 + c8 * 8];
        *(bf16x8*)&WT[(size_t)(n0 + n) * K + k0 + c8 * 8] = v;
    }
}

// ================= GEMM: 128xBN tile, BK=64, swizzled LDS, global_load_lds ====
// A [M][K] bf16 row-major; BT [N][K] bf16 (weights pre-transposed).
// 4 waves 2x2; wave computes 64 x (BN/2).
// MODE 0: QKV fused (N=1536): n<512 Q(*QSCALE,[b,h,s,d]); <1024 K[b,h,s,d]; else V^T[b,h,d,s]
// MODE 1: fp32 out + bias
// MODE 2: bf16 out + bias + exact GELU
// MODE 3: fp32 out + bias
template<int BN, int MODE>
__global__ __launch_bounds__(256) void k_gemm128(const __bf16* __restrict__ A,
                                                 const __bf16* __restrict__ BT,
                                                 const float* __restrict__ bias,
                                                 void* __restrict__ out,
                                                 int M, int N, int K) {
    __shared__ __bf16 lds[(128 + BN) * 64];
    const int tid = threadIdx.x;
    const int lane = tid & 63, w = tid >> 6;
    const int lr = lane & 15, hi = lane >> 4;
    const int wm = w >> 1, wn = w & 1;
    const int bm0 = blockIdx.y * 128, bn0 = blockIdx.x * BN;
    constexpr int NT  = BN / 32;   // n-tiles per wave
    constexpr int BIT = BN / 32;   // B stage iters
    f32x4 acc[4][NT] = {};

    for (int kt = 0; kt < K; kt += 64) {
        // ---- stage A tile [128][64], source pre-swizzled so LDS is XOR-(r&7) layout
#pragma unroll
        for (int a = 0; a < 4; a++) {
            int idx16 = a * 256 + tid;           // 16B-chunk index
            int r = idx16 >> 3, c8 = idx16 & 7;
            int k8 = c8 ^ (r & 7);
            gld_lds16(A + (size_t)(bm0 + r) * K + kt + k8 * 8,
                      (__bf16*)lds + (size_t)(a * 256 + w * 64) * 8);
        }
#pragma unroll
        for (int bq = 0; bq < BIT; bq++) {
            int idx16 = bq * 256 + tid;
            int r = idx16 >> 3, c8 = idx16 & 7;
            int k8 = c8 ^ (r & 7);
            gld_lds16(BT + (size_t)(bn0 + r) * K + kt + k8 * 8,
                      (__bf16*)lds + 128 * 64 + (size_t)(bq * 256 + w * 64) * 8);
        }
        __syncthreads();
#pragma unroll
        for (int kc = 0; kc < 2; kc++) {
            bf16x8 af[4], bf[NT];
#pragma unroll
            for (int mt = 0; mt < 4; mt++) {
                int r = wm * 64 + mt * 16 + lr;
                int c8 = (kc * 4 + hi) ^ (r & 7);
                af[mt] = *(const bf16x8*)&lds[r * 64 + c8 * 8];
            }
#pragma unroll
            for (int nt = 0; nt < NT; nt++) {
                int r = wn * (BN / 2) + nt * 16 + lr;
                int c8 = (kc * 4 + hi) ^ (r & 7);
                bf[nt] = *(const bf16x8*)&lds[128 * 64 + r * 64 + c8 * 8];
            }
#pragma unroll
            for (int mt = 0; mt < 4; mt++)
#pragma unroll
                for (int nt = 0; nt < NT; nt++)
                    acc[mt][nt] = mfma16(af[mt], bf[nt], acc[mt][nt]);
        }
        __syncthreads();
    }

#pragma unroll
    for (int mt = 0; mt < 4; mt++)
#pragma unroll
    for (int nt = 0; nt < NT; nt++)
#pragma unroll
    for (int i = 0; i < 4; i++) {
        int m = bm0 + wm * 64 + mt * 16 + hi * 4 + i;
        int n = bn0 + wn * (BN / 2) + nt * 16 + lr;
        float v = acc[mt][nt][i];
        if constexpr (MODE == 0) {
            int b = m >> 11, s = m & 2047;
            int seg = n >> 9, nn = n & 511;
            int h = nn >> 6, d = nn & 63;
            __bf16* base = (__bf16*)out;
            if (seg == 0)
                base[(((size_t)(b * N_HEADS + h)) * S_ + s) * D_K + d] = (__bf16)(v * QSCALE);
            else if (seg == 1)
                base[2097152 + (((size_t)(b * N_HEADS + h)) * S_ + s) * D_K + d] = (__bf16)v;
            else
                base[4194304 + (((size_t)(b * N_HEADS + h)) * D_K + d) * S_ + s] = (__bf16)v;
        } else if constexpr (MODE == 2) {
            v += bias[n];
            float gg = 0.5f * v * (1.0f + erff(v * 0.70710678118654752f));
            ((__bf16*)out)[(size_t)m * N + n] = (__bf16)gg;
        } else {
            ((float*)out)[(size_t)m * N + n] = v + bias[n];
        }
    }
}

// ================= flash attention v3: KV-split, no LDS, swapped QK^T =========
// grid (S/64, B*H, NSPLIT); block 256 = 4 waves; wave owns 16 q-rows (q=q0+lr),
// processes 512 keys. Writes unnormalized fp32 partial O + (m,l) per row.
__global__ __launch_bounds__(256, 8) void k_attn2(const __bf16* __restrict__ Q,
                                                  const __bf16* __restrict__ Kq,
                                                  const __bf16* __restrict__ VT,
                                                  float* __restrict__ pO,
                                                  float* __restrict__ pm,
                                                  float* __restrict__ pl) {
    const int lane = threadIdx.x & 63;
    const int w    = threadIdx.x >> 6;
    const int bh   = blockIdx.y;
    const int sp   = blockIdx.z;
    const int q0   = blockIdx.x * 64 + w * 16;
    const int lr   = lane & 15;
    const int hi   = lane >> 4;

    const __bf16* Qp = Q  + (size_t)bh * S_ * D_K;
    const __bf16* Kp = Kq + (size_t)bh * S_ * D_K;
    const __bf16* Vp = VT + (size_t)bh * D_K * S_;

    bf16x8 bq0 = *(const bf16x8*)&Qp[(size_t)(q0 + lr) * D_K + hi * 8];
    bf16x8 bq1 = *(const bf16x8*)&Qp[(size_t)(q0 + lr) * D_K + 32 + hi * 8];

    f32x4 acc[4] = {};
    float mrun = -1e30f, lrun = 0.0f;
    const int src0 = lr + ((hi & 1) << 5);
    const int src1 = src0 + 16;
    const bool csel = (hi & 2) != 0;

    const int j0 = sp * (S_ / NSPLIT);
    for (int j = j0; j < j0 + S_ / NSPLIT; j += 64) {
        f32x4 sc[4] = {};
        __builtin_amdgcn_s_setprio(1);
#pragma unroll
        for (int c = 0; c < 4; c++) {
            bf16x8 ak0 = *(const bf16x8*)&Kp[(size_t)(j + c * 16 + lr) * D_K + hi * 8];
            bf16x8 ak1 = *(const bf16x8*)&Kp[(size_t)(j + c * 16 + lr) * D_K + 32 + hi * 8];
            sc[c] = mfma16(ak0, bq0, sc[c]);
            sc[c] = mfma16(ak1, bq1, sc[c]);
        }
        __builtin_amdgcn_s_setprio(0);
        float mt0 = fmaxf(fmaxf(sc[0][0], sc[0][1]), fmaxf(sc[0][2], sc[0][3]));
        float mt1 = fmaxf(fmaxf(sc[1][0], sc[1][1]), fmaxf(sc[1][2], sc[1][3]));
        float mt2 = fmaxf(fmaxf(sc[2][0], sc[2][1]), fmaxf(sc[2][2], sc[2][3]));
        float mt3 = fmaxf(fmaxf(sc[3][0], sc[3][1]), fmaxf(sc[3][2], sc[3][3]));
        float mt = fmaxf(fmaxf(mt0, mt1), fmaxf(mt2, mt3));
        mt = fmaxf(mt, __shfl_xor(mt, 16));
        mt = fmaxf(mt, __shfl_xor(mt, 32));
        float mnew = fmaxf(mrun, mt);
        float scl = exp2f(mrun - mnew);
        mrun = mnew;
        float p[4][4];
        float ps = 0.0f;
#pragma unroll
        for (int c = 0; c < 4; c++)
#pragma unroll
            for (int i = 0; i < 4; i++) {
                p[c][i] = exp2f(sc[c][i] - mnew);
                ps += p[c][i];
            }
        ps += __shfl_xor(ps, 16);
        ps += __shfl_xor(ps, 32);
        lrun = lrun * scl + ps;
        unsigned int pk[4][2];
#pragma unroll
        for (int c = 0; c < 4; c++) {
            pk[c][0] = pack_bf16(p[c][0], p[c][1]);
            pk[c][1] = pack_bf16(p[c][2], p[c][3]);
        }
        bf16x8 pb[2];
#pragma unroll
        for (int t = 0; t < 2; t++) {
            unsigned int d0a = __shfl((int)pk[2 * t][0],     src0);
            unsigned int d0b = __shfl((int)pk[2 * t + 1][0], src0);
            unsigned int d1a = __shfl((int)pk[2 * t][1],     src0);
            unsigned int d1b = __shfl((int)pk[2 * t + 1][1], src0);
            unsigned int d2a = __shfl((int)pk[2 * t][0],     src1);
            unsigned int d2b = __shfl((int)pk[2 * t + 1][0], src1);
            unsigned int d3a = __shfl((int)pk[2 * t][1],     src1);
            unsigned int d3b = __shfl((int)pk[2 * t + 1][1], src1);
            u32x4 u = { csel ? d0b : d0a, csel ? d1b : d1a,
                        csel ? d2b : d2a, csel ? d3b : d3a };
            pb[t] = __builtin_bit_cast(bf16x8, u);
        }
#pragma unroll
        for (int dt = 0; dt < 4; dt++)
#pragma unroll
            for (int i = 0; i < 4; i++) acc[dt][i] *= scl;
        __builtin_amdgcn_s_setprio(1);
#pragma unroll
        for (int dt = 0; dt < 4; dt++) {
            bf16x8 va0 = *(const bf16x8*)&Vp[(size_t)(dt * 16 + lr) * S_ + j + hi * 8];
            bf16x8 va1 = *(const bf16x8*)&Vp[(size_t)(dt * 16 + lr) * S_ + j + 32 + hi * 8];
            acc[dt] = mfma16(va0, pb[0], acc[dt]);
            acc[dt] = mfma16(va1, pb[1], acc[dt]);
        }
        __builtin_amdgcn_s_setprio(0);
    }

    // unnormalized partial out (fp32) + per-row m,l
    float* pOw = pO + ((size_t)(sp * 16 + bh) * S_ + (q0 + lr)) * D_K;
#pragma unroll
    for (int dt = 0; dt < 4; dt++)
        *(f32x4*)&pOw[dt * 16 + hi * 4] = acc[dt];
    if (hi == 0) {
        int idx = (sp * 16 + bh) * S_ + q0 + lr;
        pm[idx] = mrun;
        pl[idx] = lrun;
    }
}

// ================= combine: merge NSPLIT partials -> ctx bf16 =================
// grid (S/4, B*H); thread: d = tid&63, row r4 = tid>>6.
__global__ __launch_bounds__(256) void k_comb(const float* __restrict__ pO,
                                              const float* __restrict__ pm,
                                              const float* __restrict__ pl,
                                              __bf16* __restrict__ ctx) {
    int tid = threadIdx.x;
    int d = tid & 63, r4 = tid >> 6;
    int q = blockIdx.x * 4 + r4, bh = blockIdx.y;
    float m[NSPLIT], l[NSPLIT];
#pragma unroll
    for (int sp = 0; sp < NSPLIT; sp++) {
        int idx = (sp * 16 + bh) * S_ + q;
        m[sp] = pm[idx];
        l[sp] = pl[idx];
    }
    float ms = m[0];
#pragma unroll
    for (int sp = 1; sp < NSPLIT; sp++) ms = fmaxf(ms, m[sp]);
    float ls = 0.0f, o = 0.0f;
#pragma unroll
    for (int sp = 0; sp < NSPLIT; sp++) {
        float wsp = exp2f(m[sp] - ms);
        ls += wsp * l[sp];
        o  += wsp * pO[((size_t)(sp * 16 + bh) * S_ + q) * D_K + d];
    }
    int b = bh >> 3, h = bh & 7;
    ctx[((size_t)(b * S_ + q)) * D_MODEL + h * D_K + d] = (__bf16)(o / ls);
}

// ================= LayerNorm: y = LN(base + delta)*g + be =====================
template<int WRITE_BF16>
__global__ __launch_bounds__(256) void k_ln(const float* __restrict__ base,
                                            const float* __restrict__ delta,
                                            const float* __restrict__ g,
                                            const float* __restrict__ be,
                                            float* __restrict__ outf,
                                            __bf16* __restrict__ outb) {
    int row  = blockIdx.x * 4 + (threadIdx.x >> 6);
    int lane = threadIdx.x & 63;
    const float4* A  = (const float4*)(base  + (size_t)row * D_MODEL);
    const float4* Bv = (const float4*)(delta + (size_t)row * D_MODEL);
    float4 a0 = A[lane],  a1 = A[lane + 64];
    float4 b0 = Bv[lane], b1 = Bv[lane + 64];
    float v[8] = { a0.x + b0.x, a0.y + b0.y, a0.z + b0.z, a0.w + b0.w,
                   a1.x + b1.x, a1.y + b1.y, a1.z + b1.z, a1.w + b1.w };
    float s1 = 0.0f, s2 = 0.0f;
#pragma unroll
    for (int j = 0; j < 8; j++) { s1 += v[j]; s2 += v[j] * v[j]; }
#pragma unroll
    for (int m = 1; m <= 32; m <<= 1) {
        s1 += __shfl_xor(s1, m);
        s2 += __shfl_xor(s2, m);
    }
    float mean = s1 * (1.0f / D_MODEL);
    float var  = s2 * (1.0f / D_MODEL) - mean * mean;
    float rstd = rsqrtf(var + 1e-5f);
    const float4* G  = (const float4*)g;
    const float4* Be = (const float4*)be;
    float4 g0 = G[lane],  g1v = G[lane + 64];
    float4 e0 = Be[lane], e1  = Be[lane + 64];
    float y[8];
    y[0] = (v[0] - mean) * rstd * g0.x  + e0.x;
    y[1] = (v[1] - mean) * rstd * g0.y  + e0.y;
    y[2] = (v[2] - mean) * rstd * g0.z  + e0.z;
    y[3] = (v[3] - mean) * rstd * g0.w  + e0.w;
    y[4] = (v[4] - mean) * rstd * g1v.x + e1.x;
    y[5] = (v[5] - mean) * rstd * g1v.y + e1.y;
    y[6] = (v[6] - mean) * rstd * g1v.z + e1.z;
    y[7] = (v[7] - mean) * rstd * g1v.w + e1.w;
    float4* O = (float4*)(outf + (size_t)row * D_MODEL);
    O[lane]      = make_float4(y[0], y[1], y[2], y[3]);
    O[lane + 64] = make_float4(y[4], y[5], y[6], y[7]);
    if constexpr (WRITE_BF16) {
        bf16x4 o0 = { (__bf16)y[0], (__bf16)y[1], (__bf16)y[2], (__bf16)y[3] };
        bf16x4 o1 = { (__bf16)y[4], (__bf16)y[5], (__bf16)y[6], (__bf16)y[7] };
        *(bf16x4*)&outb[(size_t)row * D_MODEL + lane * 4]       = o0;
        *(bf16x4*)&outb[(size_t)row * D_MODEL + 256 + lane * 4] = o1;
    }
}

extern "C" void kernel_launch(void* const* d_in, const int* in_sizes, int n_in,
                              void* d_out, int out_size, void* d_ws, size_t ws_size,
                              hipStream_t stream) {
    const float* x    = (const float*)d_in[0];
    const float* wq   = (const float*)d_in[2];
    const float* wk   = (const float*)d_in[3];
    const float* wv   = (const float*)d_in[4];
    const float* wo   = (const float*)d_in[5];
    const float* wo_b = (const float*)d_in[6];
    const float* w1   = (const float*)d_in[12];
    const float* b1   = (const float*)d_in[13];
    const float* w2   = (const float*)d_in[14];
    const float* b2   = (const float*)d_in[15];
    const float* g1   = (const float*)d_in[16];
    const float* be1  = (const float*)d_in[17];
    const float* g2   = (const float*)d_in[18];
    const float* be2  = (const float*)d_in[19];
    float* out = (float*)d_out;

    char* ws = (char*)d_ws;
    size_t off = 0;
    auto alloc = [&](size_t bytes) {
        void* p = ws + off;
        off += (bytes + 255) & ~(size_t)255;
        return p;
    };
    __bf16* xb    = (__bf16*)alloc((size_t)M_TOT * D_MODEL * 2);
    __bf16* wqkvT = (__bf16*)alloc((size_t)3 * D_MODEL * D_MODEL * 2);
    __bf16* woT   = (__bf16*)alloc((size_t)D_MODEL * D_MODEL * 2);
    __bf16* w1T   = (__bf16*)alloc((size_t)D_MODEL * D_FF * 2);
    __bf16* w2T   = (__bf16*)alloc((size_t)D_FF * D_MODEL * 2);
    __bf16* qkv   = (__bf16*)alloc((size_t)3 * M_TOT * D_MODEL * 2); // Q | K | V^T
    __bf16* ctx   = (__bf16*)alloc((size_t)M_TOT * D_MODEL * 2);
    float*  aout  = (float*)alloc((size_t)M_TOT * D_MODEL * 4);
    float*  hf    = (float*)alloc((size_t)M_TOT * D_MODEL * 4);
    __bf16* hb    = (__bf16*)alloc((size_t)M_TOT * D_MODEL * 2);
    __bf16* ffb   = (__bf16*)alloc((size_t)M_TOT * D_FF * 2);
    float*  ff2   = (float*)alloc((size_t)M_TOT * D_MODEL * 4);
    float*  pO    = (float*)alloc((size_t)NSPLIT * 16 * S_ * D_K * 4); // 32 MB
    float*  pm    = (float*)alloc((size_t)NSPLIT * 16 * S_ * 4);
    float*  pl    = (float*)alloc((size_t)NSPLIT * 16 * S_ * 4);
    (void)ws_size; (void)in_sizes; (void)n_in; (void)out_size;

    __bf16* Qb  = qkv;
    __bf16* Kb  = qkv + (size_t)M_TOT * D_MODEL;
    __bf16* VTb = qkv + (size_t)2 * M_TOT * D_MODEL;

    dim3 blk(256);
    k_prep<<<dim3(2048 + 768), blk, 0, stream>>>(x, wq, wk, wv, wo, w1, w2,
                                                 xb, wqkvT, woT, w1T, w2T);
    k_gemm128<128, 0><<<dim3(12, 32), blk, 0, stream>>>(xb, wqkvT, nullptr, qkv,
                                                        M_TOT, 3 * D_MODEL, D_MODEL);
    k_attn2<<<dim3(S_ / 64, B_ * N_HEADS, NSPLIT), blk, 0, stream>>>(Qb, Kb, VTb,
                                                                     pO, pm, pl);
    k_comb<<<dim3(S_ / 4, B_ * N_HEADS), blk, 0, stream>>>(pO, pm, pl, ctx);
    k_gemm128<64, 1><<<dim3(8, 32), blk, 0, stream>>>(ctx, woT, wo_b, aout,
                                                      M_TOT, D_MODEL, D_MODEL);
    k_ln<1><<<dim3(M_TOT / 4), blk, 0, stream>>>(x, aout, g1, be1, hf, hb);
    k_gemm128<128, 2><<<dim3(16, 32), blk, 0, stream>>>(hb, w1T, b1, ffb,
                                                        M_TOT, D_FF, D_MODEL);
    k_gemm128<64, 3><<<dim3(8, 32), blk, 0, stream>>>(ffb, w2T, b2, ff2,
                                                      M_TOT, D_MODEL, D_FF);
    k_ln<0><<<dim3(M_TOT / 4), blk, 0, stream>>>(hf, ff2, g2, be2, out, nullptr);
}

// Round 14
// 278.153 us; speedup vs baseline: 1.2214x; 1.2214x over previous
//
#include <hip/hip_runtime.h>
#include <hip/hip_bf16.h>
#include <math.h>

#define D_MODEL 512
#define N_HEADS 8
#define D_K     64
#define D_FF    2048
#define B_      2
#define S_      2048
#define M_TOT   (B_ * S_)   // 4096
#define NSPLIT  4           // KV-axis split for attention occupancy

// log2(e) folded into Q scale: softmax(s) == 2^(s*log2e) normalized
#define QSCALE  0.18033688011112042f   // 0.125 * 1.4426950408889634

typedef __attribute__((ext_vector_type(8))) __bf16 bf16x8;
typedef __attribute__((ext_vector_type(4))) __bf16 bf16x4;
typedef __attribute__((ext_vector_type(4))) float  f32x4;
typedef __attribute__((ext_vector_type(4))) unsigned int u32x4;

static __device__ inline f32x4 mfma16(bf16x8 a, bf16x8 b, f32x4 c) {
    return __builtin_amdgcn_mfma_f32_16x16x32_bf16(a, b, c, 0, 0, 0);
}

static __device__ inline void gld_lds16(const __bf16* g, __bf16* l) {
    __builtin_amdgcn_global_load_lds(
        (const __attribute__((address_space(1))) void*)g,
        (__attribute__((address_space(3))) void*)l, 16, 0, 0);
}

static __device__ inline unsigned int pack_bf16(float a, float b) {
    union { __bf16 h; unsigned short u; } ua, ub;
    ua.h = (__bf16)a; ub.h = (__bf16)b;
    return (unsigned int)ua.u | ((unsigned int)ub.u << 16);
}

// ================= fused prep: x->bf16 + LDS-tiled weight transposes ==========
__global__ __launch_bounds__(256) void k_prep(const float* __restrict__ x,
                                              const float* __restrict__ wq,
                                              const float* __restrict__ wk,
                                              const float* __restrict__ wv,
                                              const float* __restrict__ wo,
                                              const float* __restrict__ w1,
                                              const float* __restrict__ w2,
                                              __bf16* __restrict__ xb,
                                              __bf16* __restrict__ wqkvT,
                                              __bf16* __restrict__ woT,
                                              __bf16* __restrict__ w1T,
                                              __bf16* __restrict__ w2T) {
    int bid = blockIdx.x, tid = threadIdx.x;
    if (bid < 2048) {
        int i = (bid * 256 + tid) * 4;
        float4 f = *(const float4*)(x + i);
        bf16x4 o = { (__bf16)f.x, (__bf16)f.y, (__bf16)f.z, (__bf16)f.w };
        *(bf16x4*)(xb + i) = o;
        return;
    }
    __shared__ __bf16 t64[64 * 72];   // [n][k], stride 72 (pad)
    int tt = bid - 2048;
    const float* W; __bf16* WT; int N, K, ntiles, local;
    if (tt < 256) {
        N = 512; K = 512; ntiles = 8;
        if (tt < 64)       { W = wq; WT = wqkvT;          local = tt; }
        else if (tt < 128) { W = wk; WT = wqkvT + 262144; local = tt - 64; }
        else if (tt < 192) { W = wv; WT = wqkvT + 524288; local = tt - 128; }
        else               { W = wo; WT = woT;            local = tt - 192; }
    } else if (tt < 512)   { W = w1; WT = w1T; N = 2048; K = 512;  ntiles = 32; local = tt - 256; }
    else                   { W = w2; WT = w2T; N = 512;  K = 2048; ntiles = 8;  local = tt - 512; }
    int k0 = (local / ntiles) * 64, n0 = (local % ntiles) * 64;

#pragma unroll
    for (int it = 0; it < 4; it++) {
        int i = it * 256 + tid;
        int r = i >> 4, c4 = i & 15;
        float4 v = ((const float4*)(W + (size_t)(k0 + r) * N + n0))[c4];
        t64[(c4 * 4 + 0) * 72 + r] = (__bf16)v.x;
        t64[(c4 * 4 + 1) * 72 + r] = (__bf16)v.y;
        t64[(c4 * 4 + 2) * 72 + r] = (__bf16)v.z;
        t64[(c4 * 4 + 3) * 72 + r] = (__bf16)v.w;
    }
    __syncthreads();
#pragma unroll
    for (int it = 0; it < 2; it++) {
        int j = it * 256 + tid;
        int n = j >> 3, c8 = j & 7;
        bf16x8 v = *(const bf16x8*)&t64[n * 72 + c8 * 8];
        *(bf16x8*)&WT[(size_t)(n0 + n) * K + k0 + c8 * 8] = v;
    }
}

// ================= GEMM: 128xBN tile, BK=64, swizzled LDS, global_load_lds ====
template<int BN, int MODE>
__global__ __launch_bounds__(256) void k_gemm128(const __bf16* __restrict__ A,
                                                 const __bf16* __restrict__ BT,
                                                 const float* __restrict__ bias,
                                                 void* __restrict__ out,
                                                 int M, int N, int K) {
    __shared__ __bf16 lds[(128 + BN) * 64];
    const int tid = threadIdx.x;
    const int lane = tid & 63, w = tid >> 6;
    const int lr = lane & 15, hi = lane >> 4;
    const int wm = w >> 1, wn = w & 1;
    const int bm0 = blockIdx.y * 128, bn0 = blockIdx.x * BN;
    constexpr int NT  = BN / 32;
    constexpr int BIT = BN / 32;
    f32x4 acc[4][NT] = {};

    for (int kt = 0; kt < K; kt += 64) {
#pragma unroll
        for (int a = 0; a < 4; a++) {
            int idx16 = a * 256 + tid;
            int r = idx16 >> 3, c8 = idx16 & 7;
            int k8 = c8 ^ (r & 7);
            gld_lds16(A + (size_t)(bm0 + r) * K + kt + k8 * 8,
                      (__bf16*)lds + (size_t)(a * 256 + w * 64) * 8);
        }
#pragma unroll
        for (int bq = 0; bq < BIT; bq++) {
            int idx16 = bq * 256 + tid;
            int r = idx16 >> 3, c8 = idx16 & 7;
            int k8 = c8 ^ (r & 7);
            gld_lds16(BT + (size_t)(bn0 + r) * K + kt + k8 * 8,
                      (__bf16*)lds + 128 * 64 + (size_t)(bq * 256 + w * 64) * 8);
        }
        __syncthreads();
#pragma unroll
        for (int kc = 0; kc < 2; kc++) {
            bf16x8 af[4], bf[NT];
#pragma unroll
            for (int mt = 0; mt < 4; mt++) {
                int r = wm * 64 + mt * 16 + lr;
                int c8 = (kc * 4 + hi) ^ (r & 7);
                af[mt] = *(const bf16x8*)&lds[r * 64 + c8 * 8];
            }
#pragma unroll
            for (int nt = 0; nt < NT; nt++) {
                int r = wn * (BN / 2) + nt * 16 + lr;
                int c8 = (kc * 4 + hi) ^ (r & 7);
                bf[nt] = *(const bf16x8*)&lds[128 * 64 + r * 64 + c8 * 8];
            }
#pragma unroll
            for (int mt = 0; mt < 4; mt++)
#pragma unroll
                for (int nt = 0; nt < NT; nt++)
                    acc[mt][nt] = mfma16(af[mt], bf[nt], acc[mt][nt]);
        }
        __syncthreads();
    }

#pragma unroll
    for (int mt = 0; mt < 4; mt++)
#pragma unroll
    for (int nt = 0; nt < NT; nt++)
#pragma unroll
    for (int i = 0; i < 4; i++) {
        int m = bm0 + wm * 64 + mt * 16 + hi * 4 + i;
        int n = bn0 + wn * (BN / 2) + nt * 16 + lr;
        float v = acc[mt][nt][i];
        if constexpr (MODE == 0) {
            int b = m >> 11, s = m & 2047;
            int seg = n >> 9, nn = n & 511;
            int h = nn >> 6, d = nn & 63;
            __bf16* base = (__bf16*)out;
            if (seg == 0)
                base[(((size_t)(b * N_HEADS + h)) * S_ + s) * D_K + d] = (__bf16)(v * QSCALE);
            else if (seg == 1)
                base[2097152 + (((size_t)(b * N_HEADS + h)) * S_ + s) * D_K + d] = (__bf16)v;
            else
                base[4194304 + (((size_t)(b * N_HEADS + h)) * D_K + d) * S_ + s] = (__bf16)v;
        } else if constexpr (MODE == 2) {
            v += bias[n];
            float gg = 0.5f * v * (1.0f + erff(v * 0.70710678118654752f));
            ((__bf16*)out)[(size_t)m * N + n] = (__bf16)gg;
        } else {
            ((float*)out)[(size_t)m * N + n] = v + bias[n];
        }
    }
}

// ================= flash attention v4: KV-split + LDS-staged K/V tiles ========
// grid (S/64, B*H, NSPLIT); block 256 = 4 waves; wave owns 16 q-rows (q=q0+lr).
// Per 64-key tile: stage K[64][64] and V^T[64][64] into LDS once per block
// (coalesced gld_lds16, XOR-(r&7) pre-swizzled source), then all 4 waves read
// fragments via swizzled ds_read_b128 (2-way conflicts = free).
__global__ __launch_bounds__(256, 8) void k_attn2(const __bf16* __restrict__ Q,
                                                  const __bf16* __restrict__ Kq,
                                                  const __bf16* __restrict__ VT,
                                                  float* __restrict__ pO,
                                                  float* __restrict__ pm,
                                                  float* __restrict__ pl) {
    __shared__ __bf16 Kl[64 * 64];   // 8 KB
    __shared__ __bf16 Vl[64 * 64];   // 8 KB
    const int tid  = threadIdx.x;
    const int lane = tid & 63;
    const int w    = tid >> 6;
    const int bh   = blockIdx.y;
    const int sp   = blockIdx.z;
    const int q0   = blockIdx.x * 64 + w * 16;
    const int lr   = lane & 15;
    const int hi   = lane >> 4;

    const __bf16* Qp = Q  + (size_t)bh * S_ * D_K;
    const __bf16* Kp = Kq + (size_t)bh * S_ * D_K;
    const __bf16* Vp = VT + (size_t)bh * D_K * S_;

    bf16x8 bq0 = *(const bf16x8*)&Qp[(size_t)(q0 + lr) * D_K + hi * 8];
    bf16x8 bq1 = *(const bf16x8*)&Qp[(size_t)(q0 + lr) * D_K + 32 + hi * 8];

    f32x4 acc[4] = {};
    float mrun = -1e30f, lrun = 0.0f;
    const int src0 = lr + ((hi & 1) << 5);
    const int src1 = src0 + 16;
    const bool csel = (hi & 2) != 0;

    const int j0 = sp * (S_ / NSPLIT);
    for (int j = j0; j < j0 + S_ / NSPLIT; j += 64) {
        // ---- stage K tile [64 keys][64 d] and V^T tile [64 d][64 keys] ----
        __syncthreads();   // previous tile's reads complete before overwrite
#pragma unroll
        for (int it = 0; it < 2; it++) {
            int idx16 = it * 256 + tid;
            int r = idx16 >> 3, c8 = idx16 & 7;
            int k8 = c8 ^ (r & 7);   // pre-swizzled source -> XOR LDS layout
            gld_lds16(Kp + (size_t)(j + r) * D_K + k8 * 8,
                      Kl + (size_t)(it * 256 + w * 64) * 8);
            gld_lds16(Vp + (size_t)r * S_ + j + k8 * 8,
                      Vl + (size_t)(it * 256 + w * 64) * 8);
        }
        asm volatile("s_waitcnt vmcnt(0)" ::: "memory");
        __syncthreads();

        // ---- QK^T from LDS fragments ----
        f32x4 sc[4] = {};
        __builtin_amdgcn_s_setprio(1);
#pragma unroll
        for (int c = 0; c < 4; c++) {
            int r = c * 16 + lr;
            bf16x8 ak0 = *(const bf16x8*)&Kl[r * 64 + (hi ^ (r & 7)) * 8];
            bf16x8 ak1 = *(const bf16x8*)&Kl[r * 64 + ((4 + hi) ^ (r & 7)) * 8];
            sc[c] = mfma16(ak0, bq0, sc[c]);
            sc[c] = mfma16(ak1, bq1, sc[c]);
        }
        __builtin_amdgcn_s_setprio(0);

        float mt0 = fmaxf(fmaxf(sc[0][0], sc[0][1]), fmaxf(sc[0][2], sc[0][3]));
        float mt1 = fmaxf(fmaxf(sc[1][0], sc[1][1]), fmaxf(sc[1][2], sc[1][3]));
        float mt2 = fmaxf(fmaxf(sc[2][0], sc[2][1]), fmaxf(sc[2][2], sc[2][3]));
        float mt3 = fmaxf(fmaxf(sc[3][0], sc[3][1]), fmaxf(sc[3][2], sc[3][3]));
        float mt = fmaxf(fmaxf(mt0, mt1), fmaxf(mt2, mt3));
        mt = fmaxf(mt, __shfl_xor(mt, 16));
        mt = fmaxf(mt, __shfl_xor(mt, 32));
        float mnew = fmaxf(mrun, mt);
        float scl = exp2f(mrun - mnew);
        mrun = mnew;
        float p[4][4];
        float ps = 0.0f;
#pragma unroll
        for (int c = 0; c < 4; c++)
#pragma unroll
            for (int i = 0; i < 4; i++) {
                p[c][i] = exp2f(sc[c][i] - mnew);
                ps += p[c][i];
            }
        ps += __shfl_xor(ps, 16);
        ps += __shfl_xor(ps, 32);
        lrun = lrun * scl + ps;
        unsigned int pk[4][2];
#pragma unroll
        for (int c = 0; c < 4; c++) {
            pk[c][0] = pack_bf16(p[c][0], p[c][1]);
            pk[c][1] = pack_bf16(p[c][2], p[c][3]);
        }
        bf16x8 pb[2];
#pragma unroll
        for (int t = 0; t < 2; t++) {
            unsigned int d0a = __shfl((int)pk[2 * t][0],     src0);
            unsigned int d0b = __shfl((int)pk[2 * t + 1][0], src0);
            unsigned int d1a = __shfl((int)pk[2 * t][1],     src0);
            unsigned int d1b = __shfl((int)pk[2 * t + 1][1], src0);
            unsigned int d2a = __shfl((int)pk[2 * t][0],     src1);
            unsigned int d2b = __shfl((int)pk[2 * t + 1][0], src1);
            unsigned int d3a = __shfl((int)pk[2 * t][1],     src1);
            unsigned int d3b = __shfl((int)pk[2 * t + 1][1], src1);
            u32x4 u = { csel ? d0b : d0a, csel ? d1b : d1a,
                        csel ? d2b : d2a, csel ? d3b : d3a };
            pb[t] = __builtin_bit_cast(bf16x8, u);
        }
#pragma unroll
        for (int dt = 0; dt < 4; dt++)
#pragma unroll
            for (int i = 0; i < 4; i++) acc[dt][i] *= scl;

        // ---- PV from LDS fragments ----
        __builtin_amdgcn_s_setprio(1);
#pragma unroll
        for (int dt = 0; dt < 4; dt++) {
            int r = dt * 16 + lr;
            bf16x8 va0 = *(const bf16x8*)&Vl[r * 64 + (hi ^ (r & 7)) * 8];
            bf16x8 va1 = *(const bf16x8*)&Vl[r * 64 + ((4 + hi) ^ (r & 7)) * 8];
            acc[dt] = mfma16(va0, pb[0], acc[dt]);
            acc[dt] = mfma16(va1, pb[1], acc[dt]);
        }
        __builtin_amdgcn_s_setprio(0);
    }

    float* pOw = pO + ((size_t)(sp * 16 + bh) * S_ + (q0 + lr)) * D_K;
#pragma unroll
    for (int dt = 0; dt < 4; dt++)
        *(f32x4*)&pOw[dt * 16 + hi * 4] = acc[dt];
    if (hi == 0) {
        int idx = (sp * 16 + bh) * S_ + q0 + lr;
        pm[idx] = mrun;
        pl[idx] = lrun;
    }
}

// ================= combine: merge NSPLIT partials -> ctx bf16 =================
__global__ __launch_bounds__(256) void k_comb(const float* __restrict__ pO,
                                              const float* __restrict__ pm,
                                              const float* __restrict__ pl,
                                              __bf16* __restrict__ ctx) {
    int tid = threadIdx.x;
    int d = tid & 63, r4 = tid >> 6;
    int q = blockIdx.x * 4 + r4, bh = blockIdx.y;
    float m[NSPLIT], l[NSPLIT];
#pragma unroll
    for (int sp = 0; sp < NSPLIT; sp++) {
        int idx = (sp * 16 + bh) * S_ + q;
        m[sp] = pm[idx];
        l[sp] = pl[idx];
    }
    float ms = m[0];
#pragma unroll
    for (int sp = 1; sp < NSPLIT; sp++) ms = fmaxf(ms, m[sp]);
    float ls = 0.0f, o = 0.0f;
#pragma unroll
    for (int sp = 0; sp < NSPLIT; sp++) {
        float wsp = exp2f(m[sp] - ms);
        ls += wsp * l[sp];
        o  += wsp * pO[((size_t)(sp * 16 + bh) * S_ + q) * D_K + d];
    }
    int b = bh >> 3, h = bh & 7;
    ctx[((size_t)(b * S_ + q)) * D_MODEL + h * D_K + d] = (__bf16)(o / ls);
}

// ================= LayerNorm: y = LN(base + delta)*g + be =====================
template<int WRITE_BF16>
__global__ __launch_bounds__(256) void k_ln(const float* __restrict__ base,
                                            const float* __restrict__ delta,
                                            const float* __restrict__ g,
                                            const float* __restrict__ be,
                                            float* __restrict__ outf,
                                            __bf16* __restrict__ outb) {
    int row  = blockIdx.x * 4 + (threadIdx.x >> 6);
    int lane = threadIdx.x & 63;
    const float4* A  = (const float4*)(base  + (size_t)row * D_MODEL);
    const float4* Bv = (const float4*)(delta + (size_t)row * D_MODEL);
    float4 a0 = A[lane],  a1 = A[lane + 64];
    float4 b0 = Bv[lane], b1 = Bv[lane + 64];
    float v[8] = { a0.x + b0.x, a0.y + b0.y, a0.z + b0.z, a0.w + b0.w,
                   a1.x + b1.x, a1.y + b1.y, a1.z + b1.z, a1.w + b1.w };
    float s1 = 0.0f, s2 = 0.0f;
#pragma unroll
    for (int j = 0; j < 8; j++) { s1 += v[j]; s2 += v[j] * v[j]; }
#pragma unroll
    for (int m = 1; m <= 32; m <<= 1) {
        s1 += __shfl_xor(s1, m);
        s2 += __shfl_xor(s2, m);
    }
    float mean = s1 * (1.0f / D_MODEL);
    float var  = s2 * (1.0f / D_MODEL) - mean * mean;
    float rstd = rsqrtf(var + 1e-5f);
    const float4* G  = (const float4*)g;
    const float4* Be = (const float4*)be;
    float4 g0 = G[lane],  g1v = G[lane + 64];
    float4 e0 = Be[lane], e1  = Be[lane + 64];
    float y[8];
    y[0] = (v[0] - mean) * rstd * g0.x  + e0.x;
    y[1] = (v[1] - mean) * rstd * g0.y  + e0.y;
    y[2] = (v[2] - mean) * rstd * g0.z  + e0.z;
    y[3] = (v[3] - mean) * rstd * g0.w  + e0.w;
    y[4] = (v[4] - mean) * rstd * g1v.x + e1.x;
    y[5] = (v[5] - mean) * rstd * g1v.y + e1.y;
    y[6] = (v[6] - mean) * rstd * g1v.z + e1.z;
    y[7] = (v[7] - mean) * rstd * g1v.w + e1.w;
    float4* O = (float4*)(outf + (size_t)row * D_MODEL);
    O[lane]      = make_float4(y[0], y[1], y[2], y[3]);
    O[lane + 64] = make_float4(y[4], y[5], y[6], y[7]);
    if constexpr (WRITE_BF16) {
        bf16x4 o0 = { (__bf16)y[0], (__bf16)y[1], (__bf16)y[2], (__bf16)y[3] };
        bf16x4 o1 = { (__bf16)y[4], (__bf16)y[5], (__bf16)y[6], (__bf16)y[7] };
        *(bf16x4*)&outb[(size_t)row * D_MODEL + lane * 4]       = o0;
        *(bf16x4*)&outb[(size_t)row * D_MODEL + 256 + lane * 4] = o1;
    }
}

extern "C" void kernel_launch(void* const* d_in, const int* in_sizes, int n_in,
                              void* d_out, int out_size, void* d_ws, size_t ws_size,
                              hipStream_t stream) {
    const float* x    = (const float*)d_in[0];
    const float* wq   = (const float*)d_in[2];
    const float* wk   = (const float*)d_in[3];
    const float* wv   = (const float*)d_in[4];
    const float* wo   = (const float*)d_in[5];
    const float* wo_b = (const float*)d_in[6];
    const float* w1   = (const float*)d_in[12];
    const float* b1   = (const float*)d_in[13];
    const float* w2   = (const float*)d_in[14];
    const float* b2   = (const float*)d_in[15];
    const float* g1   = (const float*)d_in[16];
    const float* be1  = (const float*)d_in[17];
    const float* g2   = (const float*)d_in[18];
    const float* be2  = (const float*)d_in[19];
    float* out = (float*)d_out;

    char* ws = (char*)d_ws;
    size_t off = 0;
    auto alloc = [&](size_t bytes) {
        void* p = ws + off;
        off += (bytes + 255) & ~(size_t)255;
        return p;
    };
    __bf16* xb    = (__bf16*)alloc((size_t)M_TOT * D_MODEL * 2);
    __bf16* wqkvT = (__bf16*)alloc((size_t)3 * D_MODEL * D_MODEL * 2);
    __bf16* woT   = (__bf16*)alloc((size_t)D_MODEL * D_MODEL * 2);
    __bf16* w1T   = (__bf16*)alloc((size_t)D_MODEL * D_FF * 2);
    __bf16* w2T   = (__bf16*)alloc((size_t)D_FF * D_MODEL * 2);
    __bf16* qkv   = (__bf16*)alloc((size_t)3 * M_TOT * D_MODEL * 2); // Q | K | V^T
    __bf16* ctx   = (__bf16*)alloc((size_t)M_TOT * D_MODEL * 2);
    float*  aout  = (float*)alloc((size_t)M_TOT * D_MODEL * 4);
    float*  hf    = (float*)alloc((size_t)M_TOT * D_MODEL * 4);
    __bf16* hb    = (__bf16*)alloc((size_t)M_TOT * D_MODEL * 2);
    __bf16* ffb   = (__bf16*)alloc((size_t)M_TOT * D_FF * 2);
    float*  ff2   = (float*)alloc((size_t)M_TOT * D_MODEL * 4);
    float*  pO    = (float*)alloc((size_t)NSPLIT * 16 * S_ * D_K * 4); // 32 MB
    float*  pm    = (float*)alloc((size_t)NSPLIT * 16 * S_ * 4);
    float*  pl    = (float*)alloc((size_t)NSPLIT * 16 * S_ * 4);
    (void)ws_size; (void)in_sizes; (void)n_in; (void)out_size;

    __bf16* Qb  = qkv;
    __bf16* Kb  = qkv + (size_t)M_TOT * D_MODEL;
    __bf16* VTb = qkv + (size_t)2 * M_TOT * D_MODEL;

    dim3 blk(256);
    k_prep<<<dim3(2048 + 768), blk, 0, stream>>>(x, wq, wk, wv, wo, w1, w2,
                                                 xb, wqkvT, woT, w1T, w2T);
    k_gemm128<128, 0><<<dim3(12, 32), blk, 0, stream>>>(xb, wqkvT, nullptr, qkv,
                                                        M_TOT, 3 * D_MODEL, D_MODEL);
    k_attn2<<<dim3(S_ / 64, B_ * N_HEADS, NSPLIT), blk, 0, stream>>>(Qb, Kb, VTb,
                                                                     pO, pm, pl);
    k_comb<<<dim3(S_ / 4, B_ * N_HEADS), blk, 0, stream>>>(pO, pm, pl, ctx);
    k_gemm128<64, 1><<<dim3(8, 32), blk, 0, stream>>>(ctx, woT, wo_b, aout,
                                                      M_TOT, D_MODEL, D_MODEL);
    k_ln<1><<<dim3(M_TOT / 4), blk, 0, stream>>>(x, aout, g1, be1, hf, hb);
    k_gemm128<128, 2><<<dim3(16, 32), blk, 0, stream>>>(hb, w1T, b1, ffb,
                                                        M_TOT, D_FF, D_MODEL);
    k_gemm128<64, 3><<<dim3(8, 32), blk, 0, stream>>>(ffb, w2T, b2, ff2,
                                                      M_TOT, D_MODEL, D_FF);
    k_ln<0><<<dim3(M_TOT / 4), blk, 0, stream>>>(hf, ff2, g2, be2, out, nullptr);
}